// Round 1
// baseline (1134.543 us; speedup 1.0000x reference)
//
#include <hip/hip_runtime.h>
#include <hip/hip_bf16.h>

// TuckerLinear: out = ((x[:,iperm] @ W^T)[:,oinv]) * alpha * pds + bias
// W = (fo0 (x) fo1 (x) fo2) . G . (fi0 (x) fi1 (x) fi2)^T, G = core as 512x512.
// Factored evaluation: 5.7 GFLOP total vs 275 GFLOP dense.
// Kernel A: per-row gather + fi contractions -> t3 (stored in d_out cols [0,512) of each row).
// Kernel B: per-8-row block: u = t3 @ G^T (fp32 reg-tiled), fo expansions, perm epilogue.

#define DIN 4096
#define DOUT 4096

__global__ __launch_bounds__(256) void tucker_kA(
    const float* __restrict__ x,
    const int*   __restrict__ iperm,
    const float* __restrict__ fi0,
    const float* __restrict__ fi1,
    const float* __restrict__ fi2,
    float*       __restrict__ t3out)   // = d_out; t3 row n at [n*4096 .. n*4096+512)
{
    __shared__ float xs[4096];         // 16 KB staged x row
    __shared__ float t1[8 * 272];      // [d][E*16+F], d-stride 272 -> 2-way max (free)
    __shared__ float t2[8 * 136];      // [d*136 + e*17 + F] -> exactly 2-way (free)
    const int t = threadIdx.x;
    const int n = blockIdx.x;

    // stage x row, coalesced float4
    {
        const float4* x4 = (const float4*)(x + (size_t)n * DIN);
        float4* xs4 = (float4*)xs;
#pragma unroll
        for (int i = 0; i < 4; ++i) xs4[t + 256 * i] = x4[t + 256 * i];
    }
    __syncthreads();

    // phase 1: t1[d,E,F] = sum_D xs[perm[D,E,F]] * fi0[D,d]   (t = E*16+F)
    {
        float acc[8];
#pragma unroll
        for (int d = 0; d < 8; ++d) acc[d] = 0.f;
#pragma unroll 4
        for (int D = 0; D < 16; ++D) {
            const int pg = iperm[D * 256 + t];   // coalesced, L1/L2 cached
            const float v = xs[pg];              // LDS gather
#pragma unroll
            for (int d = 0; d < 8; ++d) acc[d] += v * fi0[D * 8 + d];  // scalar (s_load) operands
        }
#pragma unroll
        for (int d = 0; d < 8; ++d) t1[d * 272 + t] = acc[d];
    }
    __syncthreads();

    // phase 2: t2[d,e,F] = sum_E t1[d,E,F] * fi1[E,e]
    if (t < 128) {
        const int d = t >> 4, F = t & 15;
        float acc[8];
#pragma unroll
        for (int e = 0; e < 8; ++e) acc[e] = 0.f;
#pragma unroll 4
        for (int E = 0; E < 16; ++E) {
            const float v = t1[d * 272 + E * 16 + F];
#pragma unroll
            for (int e = 0; e < 8; ++e) acc[e] += v * fi1[E * 8 + e];
        }
#pragma unroll
        for (int e = 0; e < 8; ++e) t2[d * 136 + e * 17 + F] = acc[e];
    }
    __syncthreads();

    // phase 3: t3[d,e,f] = sum_F t2[d,e,F] * fi2[F,f]; write to global
    if (t < 64) {
        const int d = t >> 3, e = t & 7;
        float acc[8];
#pragma unroll
        for (int f = 0; f < 8; ++f) acc[f] = 0.f;
#pragma unroll 4
        for (int F = 0; F < 16; ++F) {
            const float v = t2[d * 136 + e * 17 + F];
#pragma unroll
            for (int f = 0; f < 8; ++f) acc[f] += v * fi2[F * 8 + f];
        }
        float4* o4 = (float4*)(t3out + (size_t)n * DOUT + t * 8);
        o4[0] = make_float4(acc[0], acc[1], acc[2], acc[3]);
        o4[1] = make_float4(acc[4], acc[5], acc[6], acc[7]);
    }
}

__global__ __launch_bounds__(256) void tucker_kB(
    const float* __restrict__ G,       // core as 512x512 row-major
    const float* __restrict__ fo0,
    const float* __restrict__ fo1,
    const float* __restrict__ fo2,
    const float* __restrict__ bias,
    const float* __restrict__ alpha,
    const float* __restrict__ pds,
    const int*   __restrict__ oinv,
    float*       __restrict__ out)     // t3 source AND final output
{
    __shared__ float t3s[8 * 512];     // 16 KB
    __shared__ float us [8 * 512];     // 16 KB
    __shared__ float v1s[16 * 72];     // [A][b*8+c], A-stride 72 (pad 8)
    __shared__ float v2s[16 * 136];    // [A][B*8+c], A-stride 136 (pad 8)
    __shared__ float v3s[16 * 264];    // [A][B*16+C], A-stride 264 (pad 8)
    __shared__ float fos[3 * 128];     // fo0|fo1|fo2
    const int t = threadIdx.x;
    const int n0 = blockIdx.x * 8;

    if (t < 128) {
        fos[t]       = fo0[t];
        fos[128 + t] = fo1[t];
        fos[256 + t] = fo2[t];
    }
    // stage t3 for 8 rows (from our own rows' cols [0,512) — written by kernel A)
    {
        const int r = t >> 7;          // 0..1
        const int i4 = t & 127;
#pragma unroll
        for (int p = 0; p < 4; ++p) {
            const int row = r + p * 2;
            ((float4*)t3s)[row * 128 + i4] =
                *(const float4*)(out + (size_t)(n0 + row) * DOUT + i4 * 4);
        }
    }
    __syncthreads();

    // GEMM: u[r,o] = sum_i t3[r,i] * G[o,i].  thread: ol=t&63 -> o = ol+64k (8 o's),
    // rg=t>>6 -> rows {2rg, 2rg+1}. 16 fp32 accumulators.
    {
        const int ol = t & 63;
        const int rg = t >> 6;
        const float4* ta4 = (const float4*)(t3s + (rg * 2) * 512);
        const float4* tb4 = (const float4*)(t3s + (rg * 2 + 1) * 512);
        const float4* G4 = (const float4*)G;
        float acc_a[8], acc_b[8];
#pragma unroll
        for (int k = 0; k < 8; ++k) { acc_a[k] = 0.f; acc_b[k] = 0.f; }
#pragma unroll 2
        for (int i4 = 0; i4 < 128; ++i4) {
            const float4 ta = ta4[i4];   // broadcast (wave-uniform address)
            const float4 tb = tb4[i4];
#pragma unroll
            for (int k = 0; k < 8; ++k) {
                const float4 g = G4[(size_t)(ol + 64 * k) * 128 + i4];  // L2-resident stream
                acc_a[k] += g.x * ta.x + g.y * ta.y + g.z * ta.z + g.w * ta.w;
                acc_b[k] += g.x * tb.x + g.y * tb.y + g.z * tb.z + g.w * tb.w;
            }
        }
#pragma unroll
        for (int k = 0; k < 8; ++k) {
            us[(rg * 2) * 512 + ol + 64 * k]     = acc_a[k];
            us[(rg * 2 + 1) * 512 + ol + 64 * k] = acc_b[k];
        }
    }
    __syncthreads();

    const float alf = alpha[0];
    const float* fo0s = fos;
    const float* fo1s = fos + 128;
    const float* fo2s = fos + 256;

    for (int r = 0; r < 8; ++r) {
        const float* u = us + r * 512;
        // v1[A,b,c] = sum_a fo0[A,a] * u[a*64 + b*8 + c]; thread: A=t>>4, 4 outputs (bc quad)
        {
            const int A = t >> 4, bc4 = (t & 15) * 4;
            float4 acc = make_float4(0.f, 0.f, 0.f, 0.f);
#pragma unroll
            for (int a = 0; a < 8; ++a) {
                const float f = fo0s[A * 8 + a];
                const float4 uv = *(const float4*)(u + a * 64 + bc4);
                acc.x += f * uv.x; acc.y += f * uv.y; acc.z += f * uv.z; acc.w += f * uv.w;
            }
            *(float4*)(v1s + A * 72 + bc4) = acc;
        }
        __syncthreads();
        // v2[A,B,c] = sum_b fo1[B,b] * v1[A,b,c]; thread: (A,B) = (t>>4, t&15), c vector
        {
            const int A = t >> 4, B = t & 15;
            float4 lo = make_float4(0.f, 0.f, 0.f, 0.f);
            float4 hi = make_float4(0.f, 0.f, 0.f, 0.f);
#pragma unroll
            for (int b = 0; b < 8; ++b) {
                const float f = fo1s[B * 8 + b];
                const float4 p0 = *(const float4*)(v1s + A * 72 + b * 8);
                const float4 p1 = *(const float4*)(v1s + A * 72 + b * 8 + 4);
                lo.x += f * p0.x; lo.y += f * p0.y; lo.z += f * p0.z; lo.w += f * p0.w;
                hi.x += f * p1.x; hi.y += f * p1.y; hi.z += f * p1.z; hi.w += f * p1.w;
            }
            *(float4*)(v2s + A * 136 + B * 8)     = lo;
            *(float4*)(v2s + A * 136 + B * 8 + 4) = hi;
        }
        __syncthreads();
        // v3[A,B,C] = sum_c fo2[C,c] * v2[A,B,c]; thread: (A,C) = (t>>4, t&15), loop B
        {
            const int A = t >> 4, C = t & 15;
            float f2[8];
#pragma unroll
            for (int c = 0; c < 8; ++c) f2[c] = fo2s[C * 8 + c];
#pragma unroll 4
            for (int q = 0; q < 16; ++q) {
                const float4 p0 = *(const float4*)(v2s + A * 136 + q * 8);
                const float4 p1 = *(const float4*)(v2s + A * 136 + q * 8 + 4);
                const float acc = f2[0] * p0.x + f2[1] * p0.y + f2[2] * p0.z + f2[3] * p0.w
                                + f2[4] * p1.x + f2[5] * p1.y + f2[6] * p1.z + f2[7] * p1.w;
                v3s[A * 264 + q * 16 + C] = acc;
            }
        }
        __syncthreads();
        // epilogue: out[n,j] = v3[oinv[j]] * alpha * pds[j] + bias[j]
        {
            float* orow = out + (size_t)(n0 + r) * DOUT;
#pragma unroll
            for (int p = 0; p < 4; ++p) {
                const int j = p * 1024 + t * 4;
                const int4  oi = *(const int4*) (oinv + j);
                const float4 ps = *(const float4*)(pds + j);
                const float4 bs = *(const float4*)(bias + j);
                float4 res;
                res.x = v3s[(oi.x >> 8) * 264 + (oi.x & 255)] * alf * ps.x + bs.x;
                res.y = v3s[(oi.y >> 8) * 264 + (oi.y & 255)] * alf * ps.y + bs.y;
                res.z = v3s[(oi.z >> 8) * 264 + (oi.z & 255)] * alf * ps.z + bs.z;
                res.w = v3s[(oi.w >> 8) * 264 + (oi.w & 255)] * alf * ps.w + bs.w;
                *(float4*)(orow + j) = res;
            }
        }
        __syncthreads();   // v3s reads done before next row's phases
    }
}

extern "C" void kernel_launch(void* const* d_in, const int* in_sizes, int n_in,
                              void* d_out, int out_size, void* d_ws, size_t ws_size,
                              hipStream_t stream) {
    const float* x    = (const float*)d_in[0];
    const float* core = (const float*)d_in[1];
    const float* fo0  = (const float*)d_in[2];
    const float* fo1  = (const float*)d_in[3];
    const float* fo2  = (const float*)d_in[4];
    const float* fi0  = (const float*)d_in[5];
    const float* fi1  = (const float*)d_in[6];
    const float* fi2  = (const float*)d_in[7];
    const float* bias = (const float*)d_in[8];
    const float* alpha= (const float*)d_in[9];
    const float* pds  = (const float*)d_in[10];
    const int* iperm  = (const int*)d_in[11];
    const int* oinv   = (const int*)d_in[12];
    float* out = (float*)d_out;

    const int nrows = in_sizes[0] / DIN;   // 8192
    tucker_kA<<<nrows, 256, 0, stream>>>(x, iperm, fi0, fi1, fi2, out);
    tucker_kB<<<nrows / 8, 256, 0, stream>>>(core, fo0, fo1, fo2, bias, alpha, pds, oinv, out);
}

// Round 2
// 362.837 us; speedup vs baseline: 3.1269x; 3.1269x over previous
//
#include <hip/hip_runtime.h>
#include <hip/hip_bf16.h>

// TuckerLinear: out = ((x[:,iperm] @ W^T)[:,oinv]) * alpha * pds + bias
// W = (fo0 (x) fo1 (x) fo2) . G . (fi0 (x) fi1 (x) fi2)^T, G = core as 512x512.
// Factored: kA: x-gather + fi contractions -> t3 (out cols [0,512)).
//           kB: tiled fp32 GEMM u = t3 @ G^T   -> u  (out cols [512,1024)).
//           kC: fo expansions + perm/scale/bias epilogue -> full out rows.

#define DIN 4096
#define DOUT 4096

__global__ __launch_bounds__(256) void tucker_kA(
    const float* __restrict__ x,
    const int*   __restrict__ iperm,
    const float* __restrict__ fi0,
    const float* __restrict__ fi1,
    const float* __restrict__ fi2,
    float*       __restrict__ t3out)   // = d_out; t3 row n at [n*4096 .. n*4096+512)
{
    __shared__ float xs[4096];         // 16 KB staged x row
    __shared__ float t1[8 * 272];      // [d][E*16+F], d-stride 272 -> 2-way max (free)
    __shared__ float t2[8 * 136];      // [d*136 + e*17 + F] -> exactly 2-way (free)
    const int t = threadIdx.x;
    const int n = blockIdx.x;

    {
        const float4* x4 = (const float4*)(x + (size_t)n * DIN);
        float4* xs4 = (float4*)xs;
#pragma unroll
        for (int i = 0; i < 4; ++i) xs4[t + 256 * i] = x4[t + 256 * i];
    }
    __syncthreads();

    // phase 1: t1[d,E,F] = sum_D xs[perm[D,E,F]] * fi0[D,d]   (t = E*16+F)
    {
        float acc[8];
#pragma unroll
        for (int d = 0; d < 8; ++d) acc[d] = 0.f;
#pragma unroll 4
        for (int D = 0; D < 16; ++D) {
            const int pg = iperm[D * 256 + t];
            const float v = xs[pg];
#pragma unroll
            for (int d = 0; d < 8; ++d) acc[d] += v * fi0[D * 8 + d];
        }
#pragma unroll
        for (int d = 0; d < 8; ++d) t1[d * 272 + t] = acc[d];
    }
    __syncthreads();

    // phase 2: t2[d,e,F] = sum_E t1[d,E,F] * fi1[E,e]
    if (t < 128) {
        const int d = t >> 4, F = t & 15;
        float acc[8];
#pragma unroll
        for (int e = 0; e < 8; ++e) acc[e] = 0.f;
#pragma unroll 4
        for (int E = 0; E < 16; ++E) {
            const float v = t1[d * 272 + E * 16 + F];
#pragma unroll
            for (int e = 0; e < 8; ++e) acc[e] += v * fi1[E * 8 + e];
        }
#pragma unroll
        for (int e = 0; e < 8; ++e) t2[d * 136 + e * 17 + F] = acc[e];
    }
    __syncthreads();

    // phase 3: t3[d,e,f] = sum_F t2[d,e,F] * fi2[F,f]
    if (t < 64) {
        const int d = t >> 3, e = t & 7;
        float acc[8];
#pragma unroll
        for (int f = 0; f < 8; ++f) acc[f] = 0.f;
#pragma unroll 4
        for (int F = 0; F < 16; ++F) {
            const float v = t2[d * 136 + e * 17 + F];
#pragma unroll
            for (int f = 0; f < 8; ++f) acc[f] += v * fi2[F * 8 + f];
        }
        float4* o4 = (float4*)(t3out + (size_t)n * DOUT + t * 8);
        o4[0] = make_float4(acc[0], acc[1], acc[2], acc[3]);
        o4[1] = make_float4(acc[4], acc[5], acc[6], acc[7]);
    }
}

// GEMM: u[m, n] = sum_k t3[m, k] * G[n, k].  M=8192, N=512, K=512.
// Block tile 128M x 64N, Ktile=32, 256 threads, 8m x 4n per thread.
// t3 read from out[m][0:512]; u written to out[m][512+n].
__global__ __launch_bounds__(256) void tucker_kB(
    const float* __restrict__ G,       // 512x512 row-major
    float*       __restrict__ out)
{
    __shared__ float As[32 * 128];     // [k][m], 16 KB
    __shared__ float Bs[32 * 64];      // [k][n],  8 KB
    const int t  = threadIdx.x;
    const int m0 = (blockIdx.x >> 3) * 128;   // 64 M-tiles
    const int n0 = (blockIdx.x & 7)  * 64;    // 8  N-tiles

    const int tn  = t & 15;            // n = n0 + tn*4 .. +3   (coalesced u stores)
    const int tmq = t >> 4;            // m = m0 + tmq*4 (+0..3) and +64

    float acc[8][4];
#pragma unroll
    for (int i = 0; i < 8; ++i)
#pragma unroll
        for (int j = 0; j < 4; ++j) acc[i][j] = 0.f;

    for (int k0 = 0; k0 < 512; k0 += 32) {
        // stage A: 128 rows x 32 k = 1024 float4-chunks; 4 per thread, coalesced
#pragma unroll
        for (int q = 0; q < 4; ++q) {
            const int c  = t + 256 * q;
            const int m  = c >> 3;             // 0..127
            const int kc = c & 7;              // 0..7 -> k = kc*4
            const float4 v = *(const float4*)(out + (size_t)(m0 + m) * DOUT + k0 + kc * 4);
            As[(kc * 4 + 0) * 128 + m] = v.x;
            As[(kc * 4 + 1) * 128 + m] = v.y;
            As[(kc * 4 + 2) * 128 + m] = v.z;
            As[(kc * 4 + 3) * 128 + m] = v.w;
        }
        // stage B: 64 rows x 32 k = 512 chunks; 2 per thread
#pragma unroll
        for (int q = 0; q < 2; ++q) {
            const int c  = t + 256 * q;
            const int n  = c >> 3;             // 0..63
            const int kc = c & 7;
            const float4 v = *(const float4*)(G + (size_t)(n0 + n) * 512 + k0 + kc * 4);
            Bs[(kc * 4 + 0) * 64 + n] = v.x;
            Bs[(kc * 4 + 1) * 64 + n] = v.y;
            Bs[(kc * 4 + 2) * 64 + n] = v.z;
            Bs[(kc * 4 + 3) * 64 + n] = v.w;
        }
        __syncthreads();

#pragma unroll 8
        for (int k = 0; k < 32; ++k) {
            const float4 b  = *(const float4*)(Bs + k * 64  + tn * 4);
            const float4 a0 = *(const float4*)(As + k * 128 + tmq * 4);
            const float4 a1 = *(const float4*)(As + k * 128 + 64 + tmq * 4);
            const float am[8] = {a0.x, a0.y, a0.z, a0.w, a1.x, a1.y, a1.z, a1.w};
            const float bn[4] = {b.x, b.y, b.z, b.w};
#pragma unroll
            for (int i = 0; i < 8; ++i)
#pragma unroll
                for (int j = 0; j < 4; ++j) acc[i][j] += am[i] * bn[j];
        }
        __syncthreads();
    }

    // store u: 8 float4 per thread, lanes 0..15 cover 64 consecutive cols
#pragma unroll
    for (int i = 0; i < 8; ++i) {
        const int m = (i < 4) ? (tmq * 4 + i) : (64 + tmq * 4 + (i - 4));
        *(float4*)(out + (size_t)(m0 + m) * DOUT + 512 + n0 + tn * 4) =
            make_float4(acc[i][0], acc[i][1], acc[i][2], acc[i][3]);
    }
}

// Expansion + epilogue: reads u from out[row][512:1024], writes full row.
__global__ __launch_bounds__(256) void tucker_kC(
    const float* __restrict__ fo0,
    const float* __restrict__ fo1,
    const float* __restrict__ fo2,
    const float* __restrict__ bias,
    const float* __restrict__ alpha,
    const float* __restrict__ pds,
    const int*   __restrict__ oinv,
    float*       __restrict__ out)
{
    __shared__ float us [8 * 512];     // 16 KB staged u for 8 rows
    __shared__ float v1s[16 * 72];     // [A][b*8+c], stride 72
    __shared__ float v2s[16 * 136];    // [A][B*8+c], stride 136
    __shared__ float v3s[16 * 264];    // [A][B*16+C], stride 264
    __shared__ float fos[3 * 128];
    const int t = threadIdx.x;
    const int n0 = blockIdx.x * 8;

    if (t < 128) {
        fos[t]       = fo0[t];
        fos[128 + t] = fo1[t];
        fos[256 + t] = fo2[t];
    }
    {
        const int r = t >> 7;
        const int i4 = t & 127;
#pragma unroll
        for (int p = 0; p < 4; ++p) {
            const int row = r + p * 2;
            ((float4*)us)[row * 128 + i4] =
                *(const float4*)(out + (size_t)(n0 + row) * DOUT + 512 + i4 * 4);
        }
    }
    __syncthreads();

    const float alf = alpha[0];
    const float* fo0s = fos;
    const float* fo1s = fos + 128;
    const float* fo2s = fos + 256;

    for (int r = 0; r < 8; ++r) {
        const float* u = us + r * 512;
        // v1[A,b,c] = sum_a fo0[A,a] * u[a*64 + b*8 + c]
        {
            const int A = t >> 4, bc4 = (t & 15) * 4;
            float4 acc = make_float4(0.f, 0.f, 0.f, 0.f);
#pragma unroll
            for (int a = 0; a < 8; ++a) {
                const float f = fo0s[A * 8 + a];
                const float4 uv = *(const float4*)(u + a * 64 + bc4);
                acc.x += f * uv.x; acc.y += f * uv.y; acc.z += f * uv.z; acc.w += f * uv.w;
            }
            *(float4*)(v1s + A * 72 + bc4) = acc;
        }
        __syncthreads();
        // v2[A,B,c] = sum_b fo1[B,b] * v1[A,b,c]
        {
            const int A = t >> 4, B = t & 15;
            float4 lo = make_float4(0.f, 0.f, 0.f, 0.f);
            float4 hi = make_float4(0.f, 0.f, 0.f, 0.f);
#pragma unroll
            for (int b = 0; b < 8; ++b) {
                const float f = fo1s[B * 8 + b];
                const float4 p0 = *(const float4*)(v1s + A * 72 + b * 8);
                const float4 p1 = *(const float4*)(v1s + A * 72 + b * 8 + 4);
                lo.x += f * p0.x; lo.y += f * p0.y; lo.z += f * p0.z; lo.w += f * p0.w;
                hi.x += f * p1.x; hi.y += f * p1.y; hi.z += f * p1.z; hi.w += f * p1.w;
            }
            *(float4*)(v2s + A * 136 + B * 8)     = lo;
            *(float4*)(v2s + A * 136 + B * 8 + 4) = hi;
        }
        __syncthreads();
        // v3[A,B,C] = sum_c fo2[C,c] * v2[A,B,c]
        {
            const int A = t >> 4, C = t & 15;
            float f2[8];
#pragma unroll
            for (int c = 0; c < 8; ++c) f2[c] = fo2s[C * 8 + c];
#pragma unroll 4
            for (int q = 0; q < 16; ++q) {
                const float4 p0 = *(const float4*)(v2s + A * 136 + q * 8);
                const float4 p1 = *(const float4*)(v2s + A * 136 + q * 8 + 4);
                const float acc = f2[0] * p0.x + f2[1] * p0.y + f2[2] * p0.z + f2[3] * p0.w
                                + f2[4] * p1.x + f2[5] * p1.y + f2[6] * p1.z + f2[7] * p1.w;
                v3s[A * 264 + q * 16 + C] = acc;
            }
        }
        __syncthreads();
        // epilogue: out[n,j] = v3[oinv[j]] * alpha * pds[j] + bias[j]
        {
            float* orow = out + (size_t)(n0 + r) * DOUT;
#pragma unroll
            for (int p = 0; p < 4; ++p) {
                const int j = p * 1024 + t * 4;
                const int4  oi = *(const int4*) (oinv + j);
                const float4 ps = *(const float4*)(pds + j);
                const float4 bs = *(const float4*)(bias + j);
                float4 res;
                res.x = v3s[(oi.x >> 8) * 264 + (oi.x & 255)] * alf * ps.x + bs.x;
                res.y = v3s[(oi.y >> 8) * 264 + (oi.y & 255)] * alf * ps.y + bs.y;
                res.z = v3s[(oi.z >> 8) * 264 + (oi.z & 255)] * alf * ps.z + bs.z;
                res.w = v3s[(oi.w >> 8) * 264 + (oi.w & 255)] * alf * ps.w + bs.w;
                *(float4*)(orow + j) = res;
            }
        }
        __syncthreads();
    }
}

extern "C" void kernel_launch(void* const* d_in, const int* in_sizes, int n_in,
                              void* d_out, int out_size, void* d_ws, size_t ws_size,
                              hipStream_t stream) {
    const float* x    = (const float*)d_in[0];
    const float* core = (const float*)d_in[1];
    const float* fo0  = (const float*)d_in[2];
    const float* fo1  = (const float*)d_in[3];
    const float* fo2  = (const float*)d_in[4];
    const float* fi0  = (const float*)d_in[5];
    const float* fi1  = (const float*)d_in[6];
    const float* fi2  = (const float*)d_in[7];
    const float* bias = (const float*)d_in[8];
    const float* alpha= (const float*)d_in[9];
    const float* pds  = (const float*)d_in[10];
    const int* iperm  = (const int*)d_in[11];
    const int* oinv   = (const int*)d_in[12];
    float* out = (float*)d_out;

    const int nrows = in_sizes[0] / DIN;   // 8192
    tucker_kA<<<nrows, 256, 0, stream>>>(x, iperm, fi0, fi1, fi2, out);
    tucker_kB<<<(nrows / 128) * 8, 256, 0, stream>>>(core, out);
    tucker_kC<<<nrows / 8, 256, 0, stream>>>(fo0, fo1, fo2, bias, alpha, pds, oinv, out);
}

// Round 3
// 314.253 us; speedup vs baseline: 3.6103x; 1.1546x over previous
//
#include <hip/hip_runtime.h>
#include <hip/hip_bf16.h>

// TuckerLinear: out = ((x[:,iperm] @ W^T)[:,oinv]) * alpha * pds + bias
// W = (fo0 (x) fo1 (x) fo2) . G . (fi0 (x) fi1 (x) fi2)^T, G = core as 512x512.
// kA : per-row x-gather + fi contractions -> t3 (bf16, packed in out cols [0,256));
//      also converts G -> bf16 into d_ws (blocks 0..511).
// kBC: fused per-16-row block: u = t3 @ G^T via bf16 MFMA (A from L1-resident t3bf,
//      B from L2-resident Gbf, no LDS staging), then fo expansions + perm epilogue.

#define DIN 4096
#define DOUT 4096

typedef __bf16 bf16x8 __attribute__((ext_vector_type(8)));
typedef float f32x4 __attribute__((ext_vector_type(4)));

static __device__ __forceinline__ unsigned int f2bf(float f) {
    unsigned int u = __builtin_bit_cast(unsigned int, f);
    u += 0x7fffu + ((u >> 16) & 1u);     // round-to-nearest-even
    return u >> 16;
}

__global__ __launch_bounds__(256) void tucker_kA(
    const float* __restrict__ x,
    const int*   __restrict__ iperm,
    const float* __restrict__ fi0,
    const float* __restrict__ fi1,
    const float* __restrict__ fi2,
    const float* __restrict__ G,
    float*       __restrict__ out,     // t3bf row n packed at bytes [0,1024) of row n
    unsigned int* __restrict__ Gbf)    // d_ws: 512x512 bf16 (as 512x256 uint)
{
    __shared__ float xs[4096];         // 16 KB staged x row
    __shared__ float t1[8 * 272];      // [d][E*16+F], d-stride 272 -> 2-way (free)
    __shared__ float t2[8 * 136];      // [d*136 + e*17 + F] -> 2-way (free)
    const int t = threadIdx.x;
    const int n = blockIdx.x;

    // piggyback: blocks 0..511 convert G row blockIdx.x to bf16 in ws
    if (n < 512) {
        const float2 g2 = *(const float2*)(G + (size_t)n * 512 + t * 2);
        Gbf[n * 256 + t] = f2bf(g2.x) | (f2bf(g2.y) << 16);
    }

    {
        const float4* x4 = (const float4*)(x + (size_t)n * DIN);
        float4* xs4 = (float4*)xs;
#pragma unroll
        for (int i = 0; i < 4; ++i) xs4[t + 256 * i] = x4[t + 256 * i];
    }
    __syncthreads();

    // phase 1: t1[d,E,F] = sum_D xs[perm[D,E,F]] * fi0[D,d]   (t = E*16+F)
    {
        float acc[8];
#pragma unroll
        for (int d = 0; d < 8; ++d) acc[d] = 0.f;
#pragma unroll 4
        for (int D = 0; D < 16; ++D) {
            const int pg = iperm[D * 256 + t];
            const float v = xs[pg];
#pragma unroll
            for (int d = 0; d < 8; ++d) acc[d] += v * fi0[D * 8 + d];
        }
#pragma unroll
        for (int d = 0; d < 8; ++d) t1[d * 272 + t] = acc[d];
    }
    __syncthreads();

    // phase 2: t2[d,e,F] = sum_E t1[d,E,F] * fi1[E,e]
    if (t < 128) {
        const int d = t >> 4, F = t & 15;
        float acc[8];
#pragma unroll
        for (int e = 0; e < 8; ++e) acc[e] = 0.f;
#pragma unroll 4
        for (int E = 0; E < 16; ++E) {
            const float v = t1[d * 272 + E * 16 + F];
#pragma unroll
            for (int e = 0; e < 8; ++e) acc[e] += v * fi1[E * 8 + e];
        }
#pragma unroll
        for (int e = 0; e < 8; ++e) t2[d * 136 + e * 17 + F] = acc[e];
    }
    __syncthreads();

    // phase 3: t3[d,e,f] = sum_F t2[d,e,F] * fi2[F,f]; write bf16-packed
    if (t < 64) {
        const int d = t >> 3, e = t & 7;
        float acc[8];
#pragma unroll
        for (int f = 0; f < 8; ++f) acc[f] = 0.f;
#pragma unroll 4
        for (int F = 0; F < 16; ++F) {
            const float v = t2[d * 136 + e * 17 + F];
#pragma unroll
            for (int f = 0; f < 8; ++f) acc[f] += v * fi2[F * 8 + f];
        }
        uint4 pk;
        pk.x = f2bf(acc[0]) | (f2bf(acc[1]) << 16);
        pk.y = f2bf(acc[2]) | (f2bf(acc[3]) << 16);
        pk.z = f2bf(acc[4]) | (f2bf(acc[5]) << 16);
        pk.w = f2bf(acc[6]) | (f2bf(acc[7]) << 16);
        *(uint4*)((unsigned short*)(out + (size_t)n * DOUT) + t * 8) = pk;
    }
}

// Fused GEMM (bf16 MFMA) + fo expansion + epilogue. 16 rows per block.
__global__ __launch_bounds__(256) void tucker_kBC(
    const unsigned short* __restrict__ Gbf,   // [512][512] bf16
    const float* __restrict__ fo0,
    const float* __restrict__ fo1,
    const float* __restrict__ fo2,
    const float* __restrict__ bias,
    const float* __restrict__ alpha,
    const float* __restrict__ pds,
    const int*   __restrict__ oinv,
    float*       __restrict__ out)
{
    __shared__ float us [16 * 516];    // [m][n], stride 516 -> 2-way (free), 33 KB
    __shared__ float v1s[16 * 72];     // [A][b*8+c]
    __shared__ float v2s[16 * 136];    // [A][B*8+c]
    __shared__ float v3s[16 * 264];    // [A][B*16+C]
    __shared__ float fos[3 * 128];     // fo0|fo1|fo2
    const int t = threadIdx.x;
    const int lane = t & 63;
    const int w = t >> 6;              // wave 0..3: n range [w*128, w*128+128)
    const int r0 = blockIdx.x * 16;

    if (t < 128) {
        fos[t]       = fo0[t];
        fos[128 + t] = fo1[t];
        fos[256 + t] = fo2[t];
    }

    // ---- GEMM: u[m,n] = sum_k t3[r0+m,k] * G[n,k], M=16, N=512, K=512 ----
    {
        const int ml   = lane & 15;    // m for A, n-within-tile for B, col for D
        const int quad = lane >> 4;    // k sub-chunk
        const unsigned short* t3p = (const unsigned short*)(out + (size_t)(r0 + ml) * DOUT);
        f32x4 acc[8];
#pragma unroll
        for (int nt = 0; nt < 8; ++nt) acc[nt] = (f32x4){0.f, 0.f, 0.f, 0.f};

#pragma unroll 2
        for (int k0 = 0; k0 < 512; k0 += 32) {
            const bf16x8 a = *(const bf16x8*)(t3p + k0 + quad * 8);    // L1-resident
#pragma unroll
            for (int nt = 0; nt < 8; ++nt) {
                const bf16x8 b = *(const bf16x8*)(Gbf + (size_t)(w * 128 + nt * 16 + ml) * 512
                                                  + k0 + quad * 8);    // L2-resident
                acc[nt] = __builtin_amdgcn_mfma_f32_16x16x32_bf16(a, b, acc[nt], 0, 0, 0);
            }
        }
        // D layout: reg r of lane = u[m = quad*4 + r][n = ml] (+ tile base)
#pragma unroll
        for (int nt = 0; nt < 8; ++nt) {
            const int nn = w * 128 + nt * 16 + ml;
#pragma unroll
            for (int r = 0; r < 4; ++r)
                us[(quad * 4 + r) * 516 + nn] = acc[nt][r];
        }
    }
    __syncthreads();

    const float alf = alpha[0];
    const float* fo0s = fos;
    const float* fo1s = fos + 128;
    const float* fo2s = fos + 256;

    for (int r = 0; r < 16; ++r) {
        const float* u = us + r * 516;
        // v1[A,b,c] = sum_a fo0[A,a] * u[a*64 + b*8 + c]
        {
            const int A = t >> 4, bc4 = (t & 15) * 4;
            float4 acc = make_float4(0.f, 0.f, 0.f, 0.f);
#pragma unroll
            for (int a = 0; a < 8; ++a) {
                const float f = fo0s[A * 8 + a];
                const float4 uv = *(const float4*)(u + a * 64 + bc4);
                acc.x += f * uv.x; acc.y += f * uv.y; acc.z += f * uv.z; acc.w += f * uv.w;
            }
            *(float4*)(v1s + A * 72 + bc4) = acc;
        }
        __syncthreads();
        // v2[A,B,c] = sum_b fo1[B,b] * v1[A,b,c]
        {
            const int A = t >> 4, B = t & 15;
            float4 lo = make_float4(0.f, 0.f, 0.f, 0.f);
            float4 hi = make_float4(0.f, 0.f, 0.f, 0.f);
#pragma unroll
            for (int b = 0; b < 8; ++b) {
                const float f = fo1s[B * 8 + b];
                const float4 p0 = *(const float4*)(v1s + A * 72 + b * 8);
                const float4 p1 = *(const float4*)(v1s + A * 72 + b * 8 + 4);
                lo.x += f * p0.x; lo.y += f * p0.y; lo.z += f * p0.z; lo.w += f * p0.w;
                hi.x += f * p1.x; hi.y += f * p1.y; hi.z += f * p1.z; hi.w += f * p1.w;
            }
            *(float4*)(v2s + A * 136 + B * 8)     = lo;
            *(float4*)(v2s + A * 136 + B * 8 + 4) = hi;
        }
        __syncthreads();
        // v3[A,B,C] = sum_c fo2[C,c] * v2[A,B,c]
        {
            const int A = t >> 4, C = t & 15;
            float f2[8];
#pragma unroll
            for (int c = 0; c < 8; ++c) f2[c] = fo2s[C * 8 + c];
#pragma unroll 4
            for (int q = 0; q < 16; ++q) {
                const float4 p0 = *(const float4*)(v2s + A * 136 + q * 8);
                const float4 p1 = *(const float4*)(v2s + A * 136 + q * 8 + 4);
                const float acc = f2[0] * p0.x + f2[1] * p0.y + f2[2] * p0.z + f2[3] * p0.w
                                + f2[4] * p1.x + f2[5] * p1.y + f2[6] * p1.z + f2[7] * p1.w;
                v3s[A * 264 + q * 16 + C] = acc;
            }
        }
        __syncthreads();
        // epilogue: out[n,j] = v3[oinv[j]] * alpha * pds[j] + bias[j]
        {
            float* orow = out + (size_t)(r0 + r) * DOUT;
#pragma unroll
            for (int p = 0; p < 4; ++p) {
                const int j = p * 1024 + t * 4;
                const int4  oi = *(const int4*) (oinv + j);
                const float4 ps = *(const float4*)(pds + j);
                const float4 bs = *(const float4*)(bias + j);
                float4 res;
                res.x = v3s[(oi.x >> 8) * 264 + (oi.x & 255)] * alf * ps.x + bs.x;
                res.y = v3s[(oi.y >> 8) * 264 + (oi.y & 255)] * alf * ps.y + bs.y;
                res.z = v3s[(oi.z >> 8) * 264 + (oi.z & 255)] * alf * ps.z + bs.z;
                res.w = v3s[(oi.w >> 8) * 264 + (oi.w & 255)] * alf * ps.w + bs.w;
                *(float4*)(orow + j) = res;
            }
        }
        __syncthreads();
    }
}

extern "C" void kernel_launch(void* const* d_in, const int* in_sizes, int n_in,
                              void* d_out, int out_size, void* d_ws, size_t ws_size,
                              hipStream_t stream) {
    const float* x    = (const float*)d_in[0];
    const float* core = (const float*)d_in[1];
    const float* fo0  = (const float*)d_in[2];
    const float* fo1  = (const float*)d_in[3];
    const float* fo2  = (const float*)d_in[4];
    const float* fi0  = (const float*)d_in[5];
    const float* fi1  = (const float*)d_in[6];
    const float* fi2  = (const float*)d_in[7];
    const float* bias = (const float*)d_in[8];
    const float* alpha= (const float*)d_in[9];
    const float* pds  = (const float*)d_in[10];
    const int* iperm  = (const int*)d_in[11];
    const int* oinv   = (const int*)d_in[12];
    float* out = (float*)d_out;

    const int nrows = in_sizes[0] / DIN;   // 8192
    tucker_kA<<<nrows, 256, 0, stream>>>(x, iperm, fi0, fi1, fi2, core, out,
                                         (unsigned int*)d_ws);
    tucker_kBC<<<nrows / 16, 256, 0, stream>>>((const unsigned short*)d_ws,
                                               fo0, fo1, fo2, bias, alpha, pds, oinv, out);
}